// Round 7
// baseline (618.899 us; speedup 1.0000x reference)
//
#include <hip/hip_runtime.h>

// MPM P2G, quadratic B-spline, 3x3x3 stencil.
// Row-sort + row-owned LDS scatter:
//   1) counting-sort particles by (bx,by) ROW key (16384 keys/timestep)
//   2) one 64-thread block per output z-row (t,X,Y): concatenates the <=9
//      contributing source-row segments into ONE wave-uniform list, each lane
//      scatters its particle's 3 z-cells x 4 components into a 2KB LDS row
//      (ds_add), then flushes the row with plain coalesced stores.
//   -> no global atomics, no output memset, no per-lane divergent loops.
//
// Outputs (concatenated in d_out, fp32):
//   grids [T,G,G,G]   -> d_out[0 .. T*G^3)
//   gdef  [T,G,G,G,3] -> d_out[T*G^3 .. 4*T*G^3)

constexpr int   G      = 128;
constexpr int   CELLS  = G * G * G;
constexpr int   NROWK  = G * G;          // 16384 row keys per timestep
constexpr float MINN   = -15.0f;
constexpr float EXTENT = 40.0f;

__device__ __forceinline__ int3 base_cell(float x, float y, float z,
                                          float& fx, float& fy, float& fz)
{
    const float scale = (float)G / EXTENT;
    const float Xp = (x - MINN) * scale;
    const float Yp = (y - MINN) * scale;
    const float Zp = (z - MINN) * scale;
    int bx = (int)floorf(Xp - 0.5f);
    int by = (int)floorf(Yp - 0.5f);
    int bz = (int)floorf(Zp - 0.5f);
    // f from the UNclamped base (matches reference); clamp affects indices only
    fx = Xp - (float)bx; fy = Yp - (float)by; fz = Zp - (float)bz;
    bx = min(max(bx, 0), G - 3);
    by = min(max(by, 0), G - 3);
    bz = min(max(bz, 0), G - 3);
    return make_int3(bx, by, bz);
}

__device__ __forceinline__ float wsel(float f, int d)
{
    const float r0 = 1.5f - f, r1 = f - 1.0f, r2 = f - 0.5f;
    const float w0 = 0.5f * r0 * r0;
    const float w1 = 0.75f - r1 * r1;
    const float w2 = 0.5f * r2 * r2;
    return d == 0 ? w0 : (d == 1 ? w1 : w2);
}

// ---- K1: histogram by row key -----------------------------------------------
__global__ void __launch_bounds__(256)
row_hist(const float* __restrict__ xs, int* __restrict__ arr, int N)
{
    const int p = blockIdx.x * blockDim.x + threadIdx.x;
    const int t = blockIdx.y;
    if (p >= N) return;
    const long i = (long)t * N + p;
    float fx, fy, fz;
    int3 b = base_cell(xs[i*3], xs[i*3+1], xs[i*3+2], fx, fy, fz);
    atomicAdd(&arr[t * NROWK + (b.x << 7) + b.y], 1);
}

// ---- K2: per-t exclusive scan of 16384 (1 block/t, 256 thr x 64 keys) -------
__global__ void __launch_bounds__(256)
row_scan(int* __restrict__ arr)
{
    const int t = blockIdx.x, tid = threadIdx.x;
    int* a = arr + t * NROWK + tid * 64;
    int s = 0;
    for (int i = 0; i < 64; ++i) s += a[i];
    __shared__ int part[256];
    part[tid] = s;
    __syncthreads();
    const int own = s;
    for (int d = 1; d < 256; d <<= 1) {
        int v = (tid >= d) ? part[tid - d] : 0;
        __syncthreads();
        part[tid] += v;
        __syncthreads();
    }
    int run = part[tid] - own;           // exclusive prefix of this 64-chunk
    for (int i = 0; i < 64; ++i) { const int v = a[i]; a[i] = run; run += v; }
}

// ---- K3: scatter into row-sorted order (arr becomes END offsets) ------------
__global__ void __launch_bounds__(256)
scatter_rows(const float* __restrict__ xs, const float* __restrict__ def,
             int* __restrict__ arr,
             float4* __restrict__ sA, float2* __restrict__ sB, int N)
{
    const int p = blockIdx.x * blockDim.x + threadIdx.x;
    const int t = blockIdx.y;
    if (p >= N) return;
    const long i = (long)t * N + p;
    const float x = xs[i*3], y = xs[i*3+1], z = xs[i*3+2];
    float fx, fy, fz;
    int3 b = base_cell(x, y, z, fx, fy, fz);
    const int slot = atomicAdd(&arr[t * NROWK + (b.x << 7) + b.y], 1);
    const long o = (long)t * N + slot;
    sA[o] = make_float4(x, y, z, def[i*3]);
    sB[o] = make_float2(def[i*3+1], def[i*3+2]);
}

// ---- K4: one block per output z-row; wave-uniform particle list -------------
__global__ void __launch_bounds__(64)
p2g_row(const float4* __restrict__ sA, const float2* __restrict__ sB,
        const int* __restrict__ arr,
        float* __restrict__ grids, float* __restrict__ gdef, int N)
{
    const int X = blockIdx.x, Y = blockIdx.y, t = blockIdx.z;
    const int lane = threadIdx.x;

    __shared__ float sm[4][G];      // SoA: mass, d0, d1, d2 per z-cell (2 KB)
    __shared__ int s_rs[9];         // per-segment global start
    __shared__ int s_cnt[9];        // per-segment count
    __shared__ int s_d[9];          // packed (X-rx)<<2 | (Y-ry)
    __shared__ int s_so[10];        // segment prefix offsets; s_so[9] = total

    #pragma unroll
    for (int i = lane; i < 4 * G; i += 64) ((float*)sm)[i] = 0.0f;

    const int xlo = max(X - 2, 0), xhi = min(X, G - 3);
    const int ylo = max(Y - 2, 0), yhi = min(Y, G - 3);

    if (lane < 9) {
        const int rx = xlo + lane / 3;      // constant divisor
        const int ry = ylo + lane % 3;
        int beg = 0, cnt = 0;
        if (rx <= xhi && ry <= yhi) {
            const int rk = (rx << 7) + ry;
            const int e  = arr[t * NROWK + rk];
            beg = rk ? arr[t * NROWK + rk - 1] : 0;   // end(prev) = start(this)
            cnt = e - beg;
        }
        s_rs[lane]  = beg;
        s_cnt[lane] = cnt;
        s_d[lane]   = ((X - rx) << 2) | (Y - ry);
    }
    __syncthreads();
    if (lane == 0) {
        int acc = 0;
        #pragma unroll
        for (int r = 0; r < 9; ++r) { s_so[r] = acc; acc += s_cnt[r]; }
        s_so[9] = acc;
    }
    __syncthreads();

    const int total = s_so[9];
    // register copies for the segment search (static indices only)
    const int so1 = s_so[1], so2 = s_so[2], so3 = s_so[3], so4 = s_so[4];
    const int so5 = s_so[5], so6 = s_so[6], so7 = s_so[7], so8 = s_so[8];
    const long pbase = (long)t * N;

    for (int j = lane; j < total; j += 64) {
        const int r = (j >= so1) + (j >= so2) + (j >= so3) + (j >= so4)
                    + (j >= so5) + (j >= so6) + (j >= so7) + (j >= so8);
        const int idx = s_rs[r] + (j - s_so[r]);     // dynamic LDS reads (ok)
        const float4 A = sA[pbase + idx];
        const float2 B = sB[pbase + idx];
        float fx, fy, fz;
        const int3 b = base_cell(A.x, A.y, A.z, fx, fy, fz);
        const int dp  = s_d[r];
        const float wxy = wsel(fx, dp >> 2) * wsel(fy, dp & 3);

        const float r0 = 1.5f - fz, r1 = fz - 1.0f, r2 = fz - 0.5f;
        const float w0 = wxy * (0.5f * r0 * r0);
        const float w1 = wxy * (0.75f - r1 * r1);
        const float w2 = wxy * (0.5f * r2 * r2);

        const int z = b.z;                           // z, z+1, z+2 <= 127
        atomicAdd(&sm[0][z    ], w0);                // P_MASS = 1
        atomicAdd(&sm[0][z + 1], w1);
        atomicAdd(&sm[0][z + 2], w2);
        atomicAdd(&sm[1][z    ], w0 * A.w);
        atomicAdd(&sm[1][z + 1], w1 * A.w);
        atomicAdd(&sm[1][z + 2], w2 * A.w);
        atomicAdd(&sm[2][z    ], w0 * B.x);
        atomicAdd(&sm[2][z + 1], w1 * B.x);
        atomicAdd(&sm[2][z + 2], w2 * B.x);
        atomicAdd(&sm[3][z    ], w0 * B.y);
        atomicAdd(&sm[3][z + 1], w1 * B.y);
        atomicAdd(&sm[3][z + 2], w2 * B.y);
    }
    __syncthreads();

    // flush: block owns the whole (t,X,Y,*) row -> plain coalesced stores
    const long cbase = (long)t * CELLS + ((long)X << 14) + ((long)Y << 7);
    grids[cbase + lane]      = sm[0][lane];
    grids[cbase + 64 + lane] = sm[0][64 + lane];
    float* grow = gdef + cbase * 3;                  // 384 contiguous floats
    #pragma unroll
    for (int i = lane; i < 3 * G; i += 64)
        grow[i] = sm[1 + (i % 3)][i / 3];            // const div/mod -> magic mul
}

// ---- last-resort fallback: direct global atomics ----------------------------
__global__ void __launch_bounds__(256)
p2g_direct(const float* __restrict__ xs, const float* __restrict__ def,
           float* __restrict__ grids, float* __restrict__ gdef, int N)
{
    const int p = blockIdx.x * blockDim.x + threadIdx.x;
    const int t = blockIdx.y;
    if (p >= N) return;
    const long i = (long)t * N + p;
    const float dx = def[i*3], dy = def[i*3+1], dz = def[i*3+2];
    float fx, fy, fz;
    int3 b = base_cell(xs[i*3], xs[i*3+1], xs[i*3+2], fx, fy, fz);
    float wx[3], wy[3], wz[3];
    wx[0] = 0.5f*(1.5f-fx)*(1.5f-fx); wx[1] = 0.75f-(fx-1.f)*(fx-1.f); wx[2] = 0.5f*(fx-0.5f)*(fx-0.5f);
    wy[0] = 0.5f*(1.5f-fy)*(1.5f-fy); wy[1] = 0.75f-(fy-1.f)*(fy-1.f); wy[2] = 0.5f*(fy-0.5f)*(fy-0.5f);
    wz[0] = 0.5f*(1.5f-fz)*(1.5f-fz); wz[1] = 0.75f-(fz-1.f)*(fz-1.f); wz[2] = 0.5f*(fz-0.5f)*(fz-0.5f);
    const long tbase = (long)t * CELLS;
    #pragma unroll
    for (int ii = 0; ii < 3; ++ii) {
        const long xoff = tbase + (long)(b.x + ii) * (G * G);
        #pragma unroll
        for (int jj = 0; jj < 3; ++jj) {
            const float wij = wx[ii] * wy[jj];
            const long yoff = xoff + (long)(b.y + jj) * G;
            #pragma unroll
            for (int kk = 0; kk < 3; ++kk) {
                const float w = wij * wz[kk];
                const long idx = yoff + (b.z + kk);
                atomicAdd(&grids[idx], w);
                atomicAdd(&gdef[idx*3+0], w * dx);
                atomicAdd(&gdef[idx*3+1], w * dy);
                atomicAdd(&gdef[idx*3+2], w * dz);
            }
        }
    }
}

extern "C" void kernel_launch(void* const* d_in, const int* in_sizes, int n_in,
                              void* d_out, int out_size, void* d_ws, size_t ws_size,
                              hipStream_t stream)
{
    const float* xs  = (const float*)d_in[0];
    const float* def = (const float*)d_in[1];
    float* out = (float*)d_out;

    const int T = (int)(out_size / ((long)CELLS * 4));
    const int N = in_sizes[0] / (3 * T);

    float* grids = out;
    float* gdef  = out + (long)T * CELLS;

    const size_t szA   = (size_t)T * N * sizeof(float4);
    const size_t szB   = (size_t)T * N * sizeof(float2);
    const size_t szArr = (size_t)T * NROWK * sizeof(int);    // 512 KB
    const size_t need  = szA + szB + szArr;

    if (ws_size >= need) {
        char* ws = (char*)d_ws;
        float4* sA  = (float4*)ws;  ws += szA;
        float2* sB  = (float2*)ws;  ws += szB;
        int*    arr = (int*)ws;

        hipMemsetAsync(arr, 0, szArr, stream);

        dim3 pgrid((N + 255) / 256, T);
        row_hist    <<<pgrid, dim3(256), 0, stream>>>(xs, arr, N);
        row_scan    <<<dim3(T), dim3(256), 0, stream>>>(arr);
        scatter_rows<<<pgrid, dim3(256), 0, stream>>>(xs, def, arr, sA, sB, N);
        p2g_row     <<<dim3(G, G, T), dim3(64), 0, stream>>>(sA, sB, arr,
                                                             grids, gdef, N);
        return;
    }

    hipMemsetAsync(d_out, 0, (size_t)out_size * sizeof(float), stream);
    dim3 grid((N + 255) / 256, T);
    p2g_direct<<<grid, dim3(256), 0, stream>>>(xs, def, grids, gdef, N);
}